// Round 17
// baseline (108.962 us; speedup 1.0000x reference)
//
#include <hip/hip_runtime.h>
#include <hip/hip_bf16.h>
#include <type_traits>

// MHA: x[2,2048,1024] fp32; W*[1024,1024] fp32; out fp32.
// Pipeline: cvt_all->bf16 (Wq/bq pre-scaled -> exp2 domain), QKV gemm
// (128x128 4-wave, 3-slot rotating LDS, counted vmcnt; V written transposed
// into vt), flash attention (8 waves x 64 q-rows/wave), out gemm (128x64).
//
// Softmax: scores in exp2 domain; shift-free (P = exp2(S), l via ones-MFMA).

typedef __attribute__((ext_vector_type(4))) float f32x4;
typedef __attribute__((ext_vector_type(16))) float f32x16;
typedef __attribute__((ext_vector_type(8))) short s16x8;
typedef __attribute__((ext_vector_type(4))) unsigned int u32x4;

#define GLDS16(g, l)                                                       \
  __builtin_amdgcn_global_load_lds(                                        \
      (const __attribute__((address_space(1))) unsigned int*)(g),          \
      (__attribute__((address_space(3))) unsigned int*)(l), 16, 0, 0)

#define SCALE_Q 0.18033688011112042f  // 0.125 * log2(e)

__device__ __forceinline__ unsigned short f2bf(float f) {
  unsigned int u = __builtin_bit_cast(unsigned int, f);
  u += 0x7fffu + ((u >> 16) & 1u);
  return (unsigned short)(u >> 16);
}

__device__ __forceinline__ unsigned int cvtpk_bf16(float lo, float hi) {
  unsigned int r;
  asm("v_cvt_pk_bf16_f32 %0, %1, %2" : "=v"(r) : "v"(lo), "v"(hi));
  return r;
}

__device__ __forceinline__ float fexp2(float x) {
  return __builtin_amdgcn_exp2f(x);
}

// All fp32->bf16 conversions + bias concat in ONE launch.
__global__ void cvt_all(const float* __restrict__ x, const float* __restrict__ Wq,
                        const float* __restrict__ Wk, const float* __restrict__ Wv,
                        const float* __restrict__ Wo, const float* __restrict__ bq,
                        const float* __restrict__ bk, const float* __restrict__ bv,
                        unsigned short* __restrict__ xb,
                        unsigned short* __restrict__ wcat,
                        unsigned short* __restrict__ wob,
                        float* __restrict__ bcat) {
  int g = blockIdx.x * blockDim.x + threadIdx.x;
  if (g >= 2097152) {  // bias tail (fp32 copy, scaled)
    int off = (g - 2097152) * 4;
    const float* src;
    float sc = 1.0f;
    int o2 = off;
    if (off < 1024) {
      src = bq; sc = SCALE_Q;
    } else if (off < 2048) {
      src = bk; o2 = off - 1024;
    } else {
      src = bv; o2 = off - 2048;
    }
    float4 v = *reinterpret_cast<const float4*>(src + o2);
    float4 w;
    w.x = v.x * sc; w.y = v.y * sc; w.z = v.z * sc; w.w = v.w * sc;
    *reinterpret_cast<float4*>(bcat + off) = w;
    return;
  }
  const float* in;
  unsigned short* out;
  int off;
  float scale = 1.0f;
  if (g < 1048576) {
    in = x; out = xb; off = g;
  } else if (g < 1310720) {
    in = Wq; out = wcat; off = g - 1048576; scale = SCALE_Q;
  } else if (g < 1572864) {
    in = Wk; out = wcat + 1048576; off = g - 1310720;
  } else if (g < 1835008) {
    in = Wv; out = wcat + 2097152; off = g - 1572864;
  } else {
    in = Wo; out = wob; off = g - 1835008;
  }
  float4 v = *reinterpret_cast<const float4*>(in + off * 4);
  ushort4 o;
  o.x = f2bf(v.x * scale); o.y = f2bf(v.y * scale);
  o.z = f2bf(v.z * scale); o.w = f2bf(v.w * scale);
  *reinterpret_cast<ushort4*>(out + off * 4) = o;
}

// QKV GEMM: C[4096,3072] = A[4096,1024] @ B[3072,1024]^T + bias (bf16).
// 128x128 tile, 4 waves, BK=32, 3-slot rotating LDS, counted vmcnt(4),
// swizzle col^=16 when row&8. V cols (>=2048) written transposed into vtp.
__global__ __launch_bounds__(256, 3) void gemm_qkv(
    const unsigned short* __restrict__ A, const unsigned short* __restrict__ B,
    unsigned short* __restrict__ C, unsigned short* __restrict__ vtp,
    const float* __restrict__ bias) {
  __shared__ __align__(16) unsigned short As[3 * 128 * 32];
  __shared__ __align__(16) unsigned short Bs[3 * 128 * 32];

  const int tid = threadIdx.x;
  const int lane = tid & 63, wv = tid >> 6;
  const int g = lane >> 4, c16 = lane & 15;
  const int wm = wv >> 1, wn = wv & 1;
  const int bn = blockIdx.x, bm = blockIdx.y;

  const unsigned short* Ab = A + (size_t)(bm * 128) * 1024;
  const unsigned short* Bb = B + (size_t)(bn * 128) * 1024;

  const int r0 = tid >> 2, cc0 = (tid & 3) * 8;
  const int r1 = r0 + 64;
  const int cs0 = cc0 ^ ((r0 & 8) << 1);
  const int cs1 = cc0 ^ ((r1 & 8) << 1);
  const int rc = (g * 8) ^ ((c16 & 8) << 1);

  f32x4 acc[4][4] = {};

#define STG(mat, base, kt, slot)                                           \
  {                                                                        \
    GLDS16(base + (size_t)r0 * 1024 + (kt) * 32 + cs0,                     \
           mat + (slot) * 4096 + r0 * 32 + cc0);                           \
    GLDS16(base + (size_t)r1 * 1024 + (kt) * 32 + cs1,                     \
           mat + (slot) * 4096 + r1 * 32 + cc0);                           \
  }

  STG(As, Ab, 0, 0)
  STG(Bs, Bb, 0, 0)
  STG(As, Ab, 1, 1)
  STG(Bs, Bb, 1, 1)

  int slot = 0, slot2 = 2;
  for (int t = 0; t < 32; ++t) {
    if (t < 31) {
      asm volatile("s_waitcnt vmcnt(4)" ::: "memory");
    } else {
      asm volatile("s_waitcnt vmcnt(0)" ::: "memory");
    }
    __builtin_amdgcn_s_barrier();
    if (t < 30) {
      STG(As, Ab, t + 2, slot2)
      STG(Bs, Bb, t + 2, slot2)
    }
    s16x8 af[4], bf[4];
#pragma unroll
    for (int mf = 0; mf < 4; ++mf)
      af[mf] = *(const s16x8*)&As[slot * 4096 +
                                  (wm * 64 + mf * 16 + c16) * 32 + rc];
#pragma unroll
    for (int nf = 0; nf < 4; ++nf)
      bf[nf] = *(const s16x8*)&Bs[slot * 4096 +
                                  (wn * 64 + nf * 16 + c16) * 32 + rc];
    __builtin_amdgcn_s_setprio(1);
#pragma unroll
    for (int mf = 0; mf < 4; ++mf)
#pragma unroll
      for (int nf = 0; nf < 4; ++nf)
        acc[mf][nf] = __builtin_amdgcn_mfma_f32_16x16x32_bf16(
            af[mf], bf[nf], acc[mf][nf], 0, 0, 0);
    __builtin_amdgcn_s_setprio(0);
    slot = (slot == 2) ? 0 : slot + 1;
    slot2 = (slot2 == 2) ? 0 : slot2 + 1;
  }
#undef STG

#pragma unroll
  for (int mf = 0; mf < 4; ++mf) {
#pragma unroll
    for (int nf = 0; nf < 4; ++nf) {
      int col = bn * 128 + wn * 64 + nf * 16 + c16;
      float bb = bias[col];
      int row0 = bm * 128 + wm * 64 + mf * 16 + g * 4;
      if (col >= 2048) {  // V projection -> transposed into vtp
        int d = col - 2048, hh = d >> 6, dl = d & 63;
        int b_ = row0 >> 11, s = row0 & 2047;
        ushort4 pk;
        pk.x = f2bf(acc[mf][nf][0] + bb);
        pk.y = f2bf(acc[mf][nf][1] + bb);
        pk.z = f2bf(acc[mf][nf][2] + bb);
        pk.w = f2bf(acc[mf][nf][3] + bb);
        *reinterpret_cast<ushort4*>(
            vtp + ((size_t)((b_ * 16 + hh) * 64 + dl)) * 2048 + s) = pk;
      } else {
#pragma unroll
        for (int j = 0; j < 4; ++j)
          C[(size_t)(row0 + j) * 3072 + col] = f2bf(acc[mf][nf][j] + bb);
      }
    }
  }
}

// Out-projection GEMM: 128x64 tiles, 512 blocks, 2-4 blocks/CU (R16-proven).
__global__ __launch_bounds__(256, 4) void gemm_out64(
    const unsigned short* __restrict__ A, const unsigned short* __restrict__ B,
    float* __restrict__ C, const float* __restrict__ bias) {
  __shared__ __align__(16) unsigned short As[3 * 128 * 32];
  __shared__ __align__(16) unsigned short Bs[3 * 64 * 32];

  const int tid = threadIdx.x;
  const int lane = tid & 63, wv = tid >> 6;
  const int g = lane >> 4, c16 = lane & 15;
  const int wm = wv >> 1, wn = wv & 1;
  const int bn = blockIdx.x, bm = blockIdx.y;

  const unsigned short* Ab = A + (size_t)(bm * 128) * 1024;
  const unsigned short* Bb = B + (size_t)(bn * 64) * 1024;

  const int r0 = tid >> 2, cc0 = (tid & 3) * 8;
  const int r1 = r0 + 64;
  const int cs0 = cc0 ^ ((r0 & 8) << 1);
  const int cs1 = cc0 ^ ((r1 & 8) << 1);
  const int rc = (g * 8) ^ ((c16 & 8) << 1);

  f32x4 acc[4][2] = {};

#define STG64(kt, slot)                                                    \
  {                                                                        \
    GLDS16(Ab + (size_t)r0 * 1024 + (kt) * 32 + cs0,                       \
           As + (slot) * 4096 + r0 * 32 + cc0);                            \
    GLDS16(Ab + (size_t)r1 * 1024 + (kt) * 32 + cs1,                       \
           As + (slot) * 4096 + r1 * 32 + cc0);                            \
    GLDS16(Bb + (size_t)r0 * 1024 + (kt) * 32 + cs0,                       \
           Bs + (slot) * 2048 + r0 * 32 + cc0);                            \
  }

  STG64(0, 0)
  STG64(1, 1)

  int slot = 0, slot2 = 2;
  for (int t = 0; t < 32; ++t) {
    if (t < 31) {
      asm volatile("s_waitcnt vmcnt(3)" ::: "memory");
    } else {
      asm volatile("s_waitcnt vmcnt(0)" ::: "memory");
    }
    __builtin_amdgcn_s_barrier();
    if (t < 30) STG64(t + 2, slot2)
    s16x8 af[4], bf[2];
#pragma unroll
    for (int mf = 0; mf < 4; ++mf)
      af[mf] = *(const s16x8*)&As[slot * 4096 +
                                  (wm * 64 + mf * 16 + c16) * 32 + rc];
#pragma unroll
    for (int nf = 0; nf < 2; ++nf)
      bf[nf] = *(const s16x8*)&Bs[slot * 2048 +
                                  (wn * 32 + nf * 16 + c16) * 32 + rc];
    __builtin_amdgcn_s_setprio(1);
#pragma unroll
    for (int mf = 0; mf < 4; ++mf)
#pragma unroll
      for (int nf = 0; nf < 2; ++nf)
        acc[mf][nf] = __builtin_amdgcn_mfma_f32_16x16x32_bf16(
            af[mf], bf[nf], acc[mf][nf], 0, 0, 0);
    __builtin_amdgcn_s_setprio(0);
    slot = (slot == 2) ? 0 : slot + 1;
    slot2 = (slot2 == 2) ? 0 : slot2 + 1;
  }
#undef STG64

#pragma unroll
  for (int mf = 0; mf < 4; ++mf) {
#pragma unroll
    for (int nf = 0; nf < 2; ++nf) {
      int col = bn * 64 + wn * 32 + nf * 16 + c16;
      float bb = bias[col];
      int row0 = bm * 128 + wm * 64 + mf * 16 + g * 4;
#pragma unroll
      for (int j = 0; j < 4; ++j)
        C[(size_t)(row0 + j) * 1024 + col] = acc[mf][nf][j] + bb;
    }
  }
}

// Flash attention: 512 thr = 8 waves (2 halves x 4 waves), each wave owns
// 64 q-rows as TWO independent Q column-groups (g2). Each K/V LDS fragment
// is read once and feeds both g2 MFMAs -> per-block LDS reads + conflicts
// HALVED vs the 16-wave version; per-wave ILP doubled (two independent
// QK->exp->PV chains). Same R13-proven sync: 4-buffer depth-2 prefetch,
// stage -> vmcnt(8) (2 tiles x 4 glds in flight) -> barrier -> compute.
// Shift-free softmax; l via ones-MFMA; XCD-pinned bh (grid x = bh).
__global__ __launch_bounds__(512) void flash_attn(
    const unsigned short* __restrict__ qkv, const unsigned short* __restrict__ vt,
    unsigned short* __restrict__ attn) {
  // [0,64K): K bufs [half][buf0..3][4096], [64K,128K): V bufs likewise
  // merge alias (post-loop): Mo f32[256][65] @0 (66560B), Ml f32[256] @66560
  __shared__ __align__(16) char smem[131072];
  unsigned short* KsB = (unsigned short*)smem;
  unsigned short* VTsB = (unsigned short*)(smem + 65536);
  float* MoB = (float*)smem;
  float* MlB = (float*)(smem + 66560);

  const int tid = threadIdx.x;
  const int wv = tid >> 6, lane = tid & 63;
  const int half = wv >> 2, w4 = wv & 3;
  const int col = lane & 31, hi = lane >> 5;
  const int bh = blockIdx.x, qt = blockIdx.y;  // bh fastest -> XCD = bh%8
  const int b = bh >> 4, h = bh & 15;
  const int qrow0 = qt * 256 + w4 * 64;

  // staging: 256 thr per half, 2 chunks per tile per matrix (K and V)
  const int stid = tid & 255;
  const int idx0 = stid, idx1 = stid + 256;
  const int sr0 = idx0 >> 3, sq0 = (((idx0 & 7) - (sr0 >> 3)) & 7) ^ (sr0 & 7);
  const int sr1 = idx1 >> 3, sq1 = (((idx1 & 7) - (sr1 >> 3)) & 7) ^ (sr1 & 7);
  const int kbase = half * 1024;
  const unsigned short* kg0 =
      qkv + (size_t)(b * 2048 + kbase + sr0) * 3072 + 1024 + h * 64 + sq0 * 8;
  const unsigned short* kg1 =
      qkv + (size_t)(b * 2048 + kbase + sr1) * 3072 + 1024 + h * 64 + sq1 * 8;
  const unsigned short* vg0 =
      vt + (size_t)(bh * 64 + sr0) * 2048 + kbase + sq0 * 8;
  const unsigned short* vg1 =
      vt + (size_t)(bh * 64 + sr1) * 2048 + kbase + sq1 * 8;

#define STGF(kt, bf)                                                       \
  {                                                                        \
    unsigned short* kd = &KsB[(half * 4 + (bf)) * 4096];                   \
    unsigned short* vd = &VTsB[(half * 4 + (bf)) * 4096];                  \
    const size_t ko = (size_t)(kt) * 64 * 3072;                            \
    GLDS16(kg0 + ko, &kd[idx0 * 8]);                                       \
    GLDS16(kg1 + ko, &kd[idx1 * 8]);                                       \
    GLDS16(vg0 + (kt) * 64, &vd[idx0 * 8]);                                \
    GLDS16(vg1 + (kt) * 64, &vd[idx1 * 8]);                                \
  }

  // Q B-fragments for both column-groups (q = qrow0 + g2*32 + col)
  s16x8 qb[2][4];
#pragma unroll
  for (int g2 = 0; g2 < 2; ++g2)
#pragma unroll
    for (int ds = 0; ds < 4; ++ds)
      qb[g2][ds] = *(const s16x8*)(qkv +
                                   (size_t)(b * 2048 + qrow0 + g2 * 32 + col) *
                                       3072 +
                                   h * 64 + ds * 16 + hi * 8);

  s16x8 onev;
#pragma unroll
  for (int j = 0; j < 8; ++j) onev[j] = (short)0x3F80;

  f32x16 o[2][2] = {};   // [g2][n]
  f32x16 lacc[2] = {};   // [g2]

  STGF(0, 0)
  STGF(1, 1)

  for (int kt = 0; kt < 16; ++kt) {
    const int buf = kt & 3;
    const unsigned short* Kc = &KsB[(half * 4 + buf) * 4096];
    const unsigned short* Vc = &VTsB[(half * 4 + buf) * 4096];
    if (kt < 14) {  // stage kt+2 then wait for tile kt (8 loads in flight)
      STGF(kt + 2, (kt + 2) & 3)
      asm volatile("s_waitcnt vmcnt(8)" ::: "memory");
    } else if (kt == 14) {
      asm volatile("s_waitcnt vmcnt(4)" ::: "memory");
    } else {
      asm volatile("s_waitcnt vmcnt(0)" ::: "memory");
    }
    __builtin_amdgcn_s_barrier();

    // QK^T: each ka read feeds BOTH g2 groups
    f32x16 st[2][2] = {};  // [g2][kb]
    __builtin_amdgcn_s_setprio(1);
#pragma unroll
    for (int kb = 0; kb < 2; ++kb) {
#pragma unroll
      for (int ds = 0; ds < 4; ++ds) {
        int row = kb * 32 + col;
        int cs = ds * 2 + hi;
        int hoff = ((cs ^ (row & 7)) + (row >> 3)) & 7;
        s16x8 ka = *(const s16x8*)&Kc[row * 64 + hoff * 8];
        st[0][kb] = __builtin_amdgcn_mfma_f32_32x32x16_bf16(ka, qb[0][ds],
                                                            st[0][kb], 0, 0, 0);
        st[1][kb] = __builtin_amdgcn_mfma_f32_32x32x16_bf16(ka, qb[1][ds],
                                                            st[1][kb], 0, 0, 0);
      }
    }
    __builtin_amdgcn_s_setprio(0);

    // P = exp2(S), shift-free
#pragma unroll
    for (int g2 = 0; g2 < 2; ++g2)
#pragma unroll
      for (int kb = 0; kb < 2; ++kb)
#pragma unroll
        for (int r = 0; r < 16; ++r) st[g2][kb][r] = fexp2(st[g2][kb][r]);

    // cvt+permlane -> pa per g2; each vb read feeds both g2 PV MFMAs
#pragma unroll
    for (int kb = 0; kb < 2; ++kb) {
#pragma unroll
      for (int hf = 0; hf < 2; ++hf) {
        const int p0 = hf * 8;
        s16x8 pa[2];
#pragma unroll
        for (int g2 = 0; g2 < 2; ++g2) {
          unsigned int a0 = cvtpk_bf16(st[g2][kb][p0 + 0], st[g2][kb][p0 + 1]);
          unsigned int b0 = cvtpk_bf16(st[g2][kb][p0 + 4], st[g2][kb][p0 + 5]);
          unsigned int a1 = cvtpk_bf16(st[g2][kb][p0 + 2], st[g2][kb][p0 + 3]);
          unsigned int b1 = cvtpk_bf16(st[g2][kb][p0 + 6], st[g2][kb][p0 + 7]);
          asm("v_permlane32_swap_b32 %0, %1" : "+v"(a0), "+v"(b0));
          asm("v_permlane32_swap_b32 %0, %1" : "+v"(a1), "+v"(b1));
          u32x4 pw;
          pw[0] = a0; pw[1] = a1; pw[2] = b0; pw[3] = b1;
          pa[g2] = __builtin_bit_cast(s16x8, pw);
        }
        const int ks = kb * 2 + hf;
        __builtin_amdgcn_s_setprio(1);
#pragma unroll
        for (int n = 0; n < 2; ++n) {
          int row = n * 32 + col;
          int cs = ks * 2 + hi;
          int hoff = ((cs ^ (row & 7)) + (row >> 3)) & 7;
          s16x8 vb = *(const s16x8*)&Vc[row * 64 + hoff * 8];
          o[0][n] = __builtin_amdgcn_mfma_f32_32x32x16_bf16(pa[0], vb, o[0][n],
                                                            0, 0, 0);
          o[1][n] = __builtin_amdgcn_mfma_f32_32x32x16_bf16(pa[1], vb, o[1][n],
                                                            0, 0, 0);
        }
        lacc[0] =
            __builtin_amdgcn_mfma_f32_32x32x16_bf16(pa[0], onev, lacc[0], 0, 0, 0);
        lacc[1] =
            __builtin_amdgcn_mfma_f32_32x32x16_bf16(pa[1], onev, lacc[1], 0, 0, 0);
        __builtin_amdgcn_s_setprio(0);
      }
    }
  }
#undef STGF
  __syncthreads();  // merge transition: staging LDS dead, alias as Mo/Ml

  if (half == 1) {
#pragma unroll
    for (int g2 = 0; g2 < 2; ++g2) {
#pragma unroll
      for (int r = 0; r < 16; ++r) {
        int qd = (r & 3) + 8 * (r >> 2) + 4 * hi;
        int row = w4 * 64 + g2 * 32 + qd;
        MoB[row * 65 + col] = o[g2][0][r];
        MoB[row * 65 + 32 + col] = o[g2][1][r];
        if (col == 0) MlB[row] = lacc[g2][r];
      }
    }
  }
  __syncthreads();
  if (half == 0) {
#pragma unroll
    for (int g2 = 0; g2 < 2; ++g2) {
#pragma unroll
      for (int r = 0; r < 16; ++r) {
        int qd = (r & 3) + 8 * (r >> 2) + 4 * hi;
        int row = w4 * 64 + g2 * 32 + qd;
        float linv = 1.f / (lacc[g2][r] + MlB[row]);
        float v0 = (o[g2][0][r] + MoB[row * 65 + col]) * linv;
        float v1 = (o[g2][1][r] + MoB[row * 65 + 32 + col]) * linv;
        size_t base = (size_t)(b * 2048 + qt * 256 + row) * 1024 + h * 64;
        attn[base + col] = f2bf(v0);
        attn[base + 32 + col] = f2bf(v1);
      }
    }
  }
}

extern "C" void kernel_launch(void* const* d_in, const int* in_sizes, int n_in,
                              void* d_out, int out_size, void* d_ws, size_t ws_size,
                              hipStream_t stream) {
  const float* x  = (const float*)d_in[0];
  const float* Wq = (const float*)d_in[1];
  const float* bq = (const float*)d_in[2];
  const float* Wk = (const float*)d_in[3];
  const float* bk = (const float*)d_in[4];
  const float* Wv = (const float*)d_in[5];
  const float* bv = (const float*)d_in[6];
  const float* Wo = (const float*)d_in[7];
  const float* bo = (const float*)d_in[8];
  float* out = (float*)d_out;

  char* ws = (char*)d_ws;
  const size_t MB = 1024 * 1024;
  // Layout:
  //   [0,8)    xb (live -> QKV gemm), then attn (written by flash)
  //   [8,10)   wob
  //   [10,16)  wcat (live through QKV gemm)
  //   [18,42)  qkv (Q,K written; V slot unused)
  //   [42,50)  vt (written by QKV gemm epilogue)
  //   [50,..)  bcat
  unsigned short* xb   = (unsigned short*)(ws + 0);
  unsigned short* attn = (unsigned short*)(ws + 0);
  unsigned short* wob  = (unsigned short*)(ws + 8 * MB);
  unsigned short* wcat = (unsigned short*)(ws + 10 * MB);
  unsigned short* qkv  = (unsigned short*)(ws + 18 * MB);
  unsigned short* vt   = (unsigned short*)(ws + 42 * MB);
  float* bcat          = (float*)(ws + 50 * MB);

  cvt_all<<<8195, 256, 0, stream>>>(x, Wq, Wk, Wv, Wo, bq, bk, bv, xb, wcat,
                                    wob, bcat);

  gemm_qkv<<<dim3(24, 32), 256, 0, stream>>>(xb, wcat, qkv, vt, bcat);

  flash_attn<<<dim3(32, 8), 512, 0, stream>>>(qkv, vt, attn);

  gemm_out64<<<dim3(16, 32), 256, 0, stream>>>(attn, wob, out, bo);
}